// Round 4
// baseline (277.710 us; speedup 1.0000x reference)
//
#include <hip/hip_runtime.h>
#include <math.h>

#define B_   8
#define C_   256
#define CI_  128
#define N_   1024
#define HW_  32
#define CO_  256

typedef __bf16 v8bf __attribute__((ext_vector_type(8)));
typedef float  f32x4 __attribute__((ext_vector_type(4)));
typedef unsigned short ushort_t;

__device__ __forceinline__ unsigned short f2bf_rne(float f) {
    unsigned int u = __float_as_uint(f);
    unsigned int r = u + 0x7FFF + ((u >> 16) & 1);
    return (unsigned short)(r >> 16);
}
__device__ __forceinline__ float bf2f(unsigned short h) {
    return __uint_as_float(((unsigned int)h) << 16);
}
__device__ __forceinline__ v8bf ld8(const ushort_t* p) {
    return *(const v8bf*)p;
}

// ---------------------------------------------------------------------------
// P1 (merged): blocks [0,1152) split Wc; [1152,1536) split Wq/Wk/Wv;
// [1536,2560) gather strided x -> xs_t[b][n][c] bf16 hi/lo.
// Gather now loads x as float4 and keeps .x: identical bytes fetched
// (line-granular anyway) but dense sequential dwordx4 per wave instead of
// 16-line scatter -> full HBM request efficiency.
__global__ __launch_bounds__(256) void prep_all_kernel(
    const float* __restrict__ x,
    const float* __restrict__ Wc,
    const float* __restrict__ Wq, const float* __restrict__ Wk,
    const float* __restrict__ Wv,
    ushort_t* __restrict__ Whi, ushort_t* __restrict__ Wlo,
    ushort_t* __restrict__ Wp_hi, ushort_t* __restrict__ Wp_lo,
    ushort_t* __restrict__ xs_hi, ushort_t* __restrict__ xs_lo,
    float* __restrict__ meanb)
{
    __shared__ ushort_t lh[32 * 72];
    __shared__ ushort_t ll[32 * 72];
    const int bx = blockIdx.x;
    const int tid = threadIdx.x;

    if (bx < 1152) {
        if (bx == 0) {   // zero the mean accumulator (1024 floats)
            *(float4*)&meanb[tid * 4] = make_float4(0.f, 0.f, 0.f, 0.f);
        }
        int idx = bx * 256 + tid;                 // 294912
        int o = idx / 1152;
        int r = idx - o * 1152;
        int ci = r / 9;
        int tap = r - ci * 9;
        float v = Wc[idx];
        unsigned short h = f2bf_rne(v);
        unsigned short l = f2bf_rne(v - bf2f(h));
        int didx = o * 1152 + tap * 128 + ci;
        Whi[didx] = h; Wlo[didx] = l;
    } else if (bx < 1536) {
        int j = (bx - 1152) * 256 + tid;          // 98304
        int o = j >> 8, c = j & 255;
        float v = (o < 128) ? Wq[o * 256 + c]
                : (o < 256) ? Wk[(o - 128) * 256 + c]
                            : Wv[(o - 256) * 256 + c];
        unsigned short h = f2bf_rne(v);
        unsigned short l = f2bf_rne(v - bf2f(h));
        Wp_hi[j] = h; Wp_lo[j] = l;
    } else {
        const int bx2 = bx - 1536;                // 1024 blocks: b(8) x h(32) x cq(4)
        const int cq = bx2 & 3;
        const int h  = (bx2 >> 2) & 31;
        const int b  = bx2 >> 7;
        const int w = tid & 31, cg = tid >> 5;
        const float4* xrow = (const float4*)x;
        float v[8];
        #pragma unroll
        for (int i = 0; i < 8; ++i) {
            int c = cq * 64 + i * 8 + cg;
            // element (b,c,h*4,w*4) = float4 index ((b*C_+c)*4096 + h*128 + w).x
            v[i] = xrow[(size_t)(b * C_ + c) * 4096 + h * 128 + w].x;
        }
        #pragma unroll
        for (int i = 0; i < 8; ++i) {
            int cl = i * 8 + cg;
            unsigned short hi = f2bf_rne(v[i]);
            unsigned short lo = f2bf_rne(v[i] - bf2f(hi));
            lh[w * 72 + cl] = hi;
            ll[w * 72 + cl] = lo;
        }
        __syncthreads();
        const int ww = tid >> 3, cs = tid & 7;
        size_t dst = ((size_t)(b * N_) + h * 32 + ww) * 256 + cq * 64 + cs * 8;
        *(uint4*)&xs_hi[dst] = *(uint4*)&lh[ww * 72 + cs * 8];
        *(uint4*)&xs_lo[dst] = *(uint4*)&ll[ww * 72 + cs * 8];
    }
}

// ---------------------------------------------------------------------------
// K1: proj MFMA. A = Wp [o][c] hi/lo, B = xs_t [n][c] hi/lo. 3-term split.
// XCD-pinned (batch = lin&7). V-blocks use operand-swapped MFMA (same product
// set) so the register dim = m -> vectorized uint2 vB stores.
__global__ __launch_bounds__(256) void proj_mfma_kernel(
    const ushort_t* __restrict__ Wp_hi, const ushort_t* __restrict__ Wp_lo,
    const ushort_t* __restrict__ xs_hi, const ushort_t* __restrict__ xs_lo,
    ushort_t* __restrict__ qt_hi, ushort_t* __restrict__ qt_lo,
    ushort_t* __restrict__ kt_hi, ushort_t* __restrict__ kt_lo,
    ushort_t* __restrict__ vB_hi, ushort_t* __restrict__ vB_lo)
{
    const int lin = blockIdx.x + 16 * (blockIdx.y + 6 * blockIdx.z);
    const int b    = lin & 7;          // XCD pin
    const int rest = lin >> 3;         // 0..95
    const int n0 = (rest & 15) * 64;
    const int o0 = (rest >> 4) * 64;
    const int tid = threadIdx.x;
    const int l = tid & 63, wv = tid >> 6;
    const int wy = wv >> 1, wx = wv & 1;
    const int ln = l & 15, quad = l >> 4;

    const ushort_t* Ah_p[2]; const ushort_t* Al_p[2];
    const ushort_t* Bh_p[2]; const ushort_t* Bl_p[2];
    #pragma unroll
    for (int i = 0; i < 2; ++i) {
        size_t off = (size_t)(o0 + wy * 32 + i * 16 + ln) * 256 + quad * 8;
        Ah_p[i] = Wp_hi + off; Al_p[i] = Wp_lo + off;
    }
    #pragma unroll
    for (int j = 0; j < 2; ++j) {
        size_t off = ((size_t)(b * N_) + n0 + wx * 32 + j * 16 + ln) * 256 + quad * 8;
        Bh_p[j] = xs_hi + off; Bl_p[j] = xs_lo + off;
    }

    f32x4 acc[2][2];
    #pragma unroll
    for (int i = 0; i < 2; ++i)
        #pragma unroll
        for (int j = 0; j < 2; ++j) acc[i][j] = (f32x4){0.f,0.f,0.f,0.f};

    if (o0 < 256) {
        #pragma unroll 4
        for (int k0 = 0; k0 < 256; k0 += 32) {
            v8bf Ah[2], Al[2], Bh[2], Bl[2];
            #pragma unroll
            for (int i = 0; i < 2; ++i) { Ah[i] = ld8(Ah_p[i] + k0); Al[i] = ld8(Al_p[i] + k0); }
            #pragma unroll
            for (int j = 0; j < 2; ++j) { Bh[j] = ld8(Bh_p[j] + k0); Bl[j] = ld8(Bl_p[j] + k0); }
            __builtin_amdgcn_s_setprio(1);
            #pragma unroll
            for (int i = 0; i < 2; ++i)
                #pragma unroll
                for (int j = 0; j < 2; ++j) {
                    acc[i][j] = __builtin_amdgcn_mfma_f32_16x16x32_bf16(Ah[i], Bh[j], acc[i][j], 0, 0, 0);
                    acc[i][j] = __builtin_amdgcn_mfma_f32_16x16x32_bf16(Ah[i], Bl[j], acc[i][j], 0, 0, 0);
                    acc[i][j] = __builtin_amdgcn_mfma_f32_16x16x32_bf16(Al[i], Bh[j], acc[i][j], 0, 0, 0);
                }
            __builtin_amdgcn_s_setprio(0);
        }
        // q or k: transposed store [n][o], pack 4 consecutive o (regs) into 8B
        ushort_t* th = (o0 < 128) ? qt_hi : kt_hi;
        ushort_t* tl = (o0 < 128) ? qt_lo : kt_lo;
        const int ob = o0 & 127;
        #pragma unroll
        for (int i = 0; i < 2; ++i)
            #pragma unroll
            for (int j = 0; j < 2; ++j) {
                int oo = ob + wy * 32 + i * 16 + quad * 4;
                int n  = n0 + wx * 32 + j * 16 + ln;
                unsigned int h01 = 0, h23 = 0, l01 = 0, l23 = 0;
                #pragma unroll
                for (int r = 0; r < 4; ++r) {
                    float f = acc[i][j][r];
                    unsigned short hh = f2bf_rne(f);
                    unsigned short lo = f2bf_rne(f - bf2f(hh));
                    if (r < 2) { h01 |= ((unsigned)hh) << (16 * r); l01 |= ((unsigned)lo) << (16 * r); }
                    else       { h23 |= ((unsigned)hh) << (16 * (r - 2)); l23 |= ((unsigned)lo) << (16 * (r - 2)); }
                }
                size_t off = ((size_t)(b * N_) + n) * 128 + oo;
                *(uint2*)&th[off] = make_uint2(h01, h23);
                *(uint2*)&tl[off] = make_uint2(l01, l23);
            }
    } else {
        // v: operand-swapped -> acc[j][i] rows = m, cols = c
        #pragma unroll 4
        for (int k0 = 0; k0 < 256; k0 += 32) {
            v8bf Ah[2], Al[2], Bh[2], Bl[2];
            #pragma unroll
            for (int i = 0; i < 2; ++i) { Ah[i] = ld8(Ah_p[i] + k0); Al[i] = ld8(Al_p[i] + k0); }
            #pragma unroll
            for (int j = 0; j < 2; ++j) { Bh[j] = ld8(Bh_p[j] + k0); Bl[j] = ld8(Bl_p[j] + k0); }
            __builtin_amdgcn_s_setprio(1);
            #pragma unroll
            for (int j = 0; j < 2; ++j)
                #pragma unroll
                for (int i = 0; i < 2; ++i) {
                    acc[j][i] = __builtin_amdgcn_mfma_f32_16x16x32_bf16(Bh[j], Ah[i], acc[j][i], 0, 0, 0);
                    acc[j][i] = __builtin_amdgcn_mfma_f32_16x16x32_bf16(Bh[j], Al[i], acc[j][i], 0, 0, 0);
                    acc[j][i] = __builtin_amdgcn_mfma_f32_16x16x32_bf16(Bl[j], Ah[i], acc[j][i], 0, 0, 0);
                }
            __builtin_amdgcn_s_setprio(0);
        }
        // vB[b][m>>5][c][m&31]; reg dim = m (4 consecutive) -> uint2 stores
        const int mhi = (n0 >> 5) + wx;
        #pragma unroll
        for (int j = 0; j < 2; ++j)
            #pragma unroll
            for (int i = 0; i < 2; ++i) {
                int c   = (o0 - 256) + wy * 32 + i * 16 + ln;
                int mlo = j * 16 + quad * 4;
                unsigned int h01 = 0, h23 = 0, l01 = 0, l23 = 0;
                #pragma unroll
                for (int r = 0; r < 4; ++r) {
                    float f = acc[j][i][r];
                    unsigned short hh = f2bf_rne(f);
                    unsigned short lo = f2bf_rne(f - bf2f(hh));
                    if (r < 2) { h01 |= ((unsigned)hh) << (16 * r); l01 |= ((unsigned)lo) << (16 * r); }
                    else       { h23 |= ((unsigned)hh) << (16 * (r - 2)); l23 |= ((unsigned)lo) << (16 * (r - 2)); }
                }
                size_t off = (((size_t)b * 32 + mhi) * 128 + c) * 32 + mlo;
                *(uint2*)&vB_hi[off] = make_uint2(h01, h23);
                *(uint2*)&vB_lo[off] = make_uint2(l01, l23);
            }
    }
}

// ---------------------------------------------------------------------------
// K2: fused attention, 512 threads / 8 waves, XCD-pinned. Gate fp32 store
// deferred past phase 2. Accumulates mean partials (atomicAdd).
__global__ __launch_bounds__(512, 2) void attn_fused_kernel(
    const ushort_t* __restrict__ qt_hi, const ushort_t* __restrict__ qt_lo,
    const ushort_t* __restrict__ kt_hi, const ushort_t* __restrict__ kt_lo,
    const ushort_t* __restrict__ vB_hi, const ushort_t* __restrict__ vB_lo,
    float* __restrict__ gate, float* __restrict__ gv, float* __restrict__ meanb)
{
    __shared__ __align__(16) char gsm[65536];     // Gbf[32][1024] bf16, swizzled
    __shared__ float redA[8][32];
    __shared__ float redB[8][32];

    const int lin = blockIdx.x + 32 * blockIdx.y;
    const int b  = lin & 7;            // XCD pin
    const int n0 = (lin >> 3) * 32;
    const int tid = threadIdx.x;
    const int l = tid & 63, w = tid >> 6;         // w in [0,8)
    const int ln = l & 15, quad = l >> 4;
    const int Mw = w * 128;

    const ushort_t* qb_h = qt_hi + ((size_t)(b * N_) + n0) * 128;
    const ushort_t* qb_l = qt_lo + ((size_t)(b * N_) + n0) * 128;
    const ushort_t* kb_h = kt_hi + (size_t)(b * N_) * 128;
    const ushort_t* kb_l = kt_lo + (size_t)(b * N_) * 128;

    f32x4 acc[2][8];
    #pragma unroll
    for (int nt = 0; nt < 2; ++nt)
        #pragma unroll
        for (int mt = 0; mt < 8; ++mt) acc[nt][mt] = (f32x4){0.f,0.f,0.f,0.f};

    // ---- phase 1: scores (3-term bf16 split)
    #pragma unroll
    for (int c0 = 0; c0 < 128; c0 += 32) {
        v8bf Ah[2], Al[2];
        #pragma unroll
        for (int nt = 0; nt < 2; ++nt) {
            size_t aoff = (size_t)(nt * 16 + ln) * 128 + c0 + quad * 8;
            Ah[nt] = ld8(qb_h + aoff); Al[nt] = ld8(qb_l + aoff);
        }
        #pragma unroll
        for (int mt = 0; mt < 8; ++mt) {
            size_t boff = (size_t)(Mw + mt * 16 + ln) * 128 + c0 + quad * 8;
            v8bf Bh = ld8(kb_h + boff);
            v8bf Bl = ld8(kb_l + boff);
            __builtin_amdgcn_s_setprio(1);
            #pragma unroll
            for (int nt = 0; nt < 2; ++nt) {
                acc[nt][mt] = __builtin_amdgcn_mfma_f32_16x16x32_bf16(Ah[nt], Bh, acc[nt][mt], 0, 0, 0);
                acc[nt][mt] = __builtin_amdgcn_mfma_f32_16x16x32_bf16(Ah[nt], Bl, acc[nt][mt], 0, 0, 0);
                acc[nt][mt] = __builtin_amdgcn_mfma_f32_16x16x32_bf16(Al[nt], Bh, acc[nt][mt], 0, 0, 0);
            }
            __builtin_amdgcn_s_setprio(0);
        }
    }

    // ---- softmax
    float rmax[2][4];
    #pragma unroll
    for (int nt = 0; nt < 2; ++nt)
        #pragma unroll
        for (int r = 0; r < 4; ++r) {
            float m = acc[nt][0][r];
            #pragma unroll
            for (int mt = 1; mt < 8; ++mt) m = fmaxf(m, acc[nt][mt][r]);
            rmax[nt][r] = m;
        }
    #pragma unroll
    for (int nt = 0; nt < 2; ++nt)
        #pragma unroll
        for (int r = 0; r < 4; ++r) {
            float m = rmax[nt][r];
            #pragma unroll
            for (int xm = 1; xm <= 8; xm <<= 1) m = fmaxf(m, __shfl_xor(m, xm, 64));
            rmax[nt][r] = m;
        }
    if (ln == 0) {
        #pragma unroll
        for (int nt = 0; nt < 2; ++nt)
            #pragma unroll
            for (int r = 0; r < 4; ++r)
                redA[w][nt * 16 + quad * 4 + r] = rmax[nt][r];
    }
    __syncthreads();
    #pragma unroll
    for (int nt = 0; nt < 2; ++nt)
        #pragma unroll
        for (int r = 0; r < 4; ++r) {
            int row = nt * 16 + quad * 4 + r;
            float m0 = fmaxf(fmaxf(redA[0][row], redA[1][row]),
                             fmaxf(redA[2][row], redA[3][row]));
            float m1 = fmaxf(fmaxf(redA[4][row], redA[5][row]),
                             fmaxf(redA[6][row], redA[7][row]));
            rmax[nt][r] = fmaxf(m0, m1);
        }

    float rsum[2][4];
    #pragma unroll
    for (int nt = 0; nt < 2; ++nt)
        #pragma unroll
        for (int r = 0; r < 4; ++r) {
            float s = 0.f;
            #pragma unroll
            for (int mt = 0; mt < 8; ++mt) {
                float e = __expf(acc[nt][mt][r] - rmax[nt][r]);
                acc[nt][mt][r] = e;
                s += e;
            }
            rsum[nt][r] = s;
        }
    #pragma unroll
    for (int nt = 0; nt < 2; ++nt)
        #pragma unroll
        for (int r = 0; r < 4; ++r) {
            float s = rsum[nt][r];
            #pragma unroll
            for (int xm = 1; xm <= 8; xm <<= 1) s += __shfl_xor(s, xm, 64);
            rsum[nt][r] = s;
        }
    if (ln == 0) {
        #pragma unroll
        for (int nt = 0; nt < 2; ++nt)
            #pragma unroll
            for (int r = 0; r < 4; ++r)
                redB[w][nt * 16 + quad * 4 + r] = rsum[nt][r];
    }
    __syncthreads();
    #pragma unroll
    for (int nt = 0; nt < 2; ++nt)
        #pragma unroll
        for (int r = 0; r < 4; ++r) {
            int row = nt * 16 + quad * 4 + r;
            float inv = 1.0f / ((redB[0][row] + redB[1][row] + redB[2][row] + redB[3][row]) +
                                (redB[4][row] + redB[5][row] + redB[6][row] + redB[7][row]));
            #pragma unroll
            for (int mt = 0; mt < 8; ++mt) acc[nt][mt][r] *= inv;
        }

    // ---- write gate bf16 -> swizzled LDS only (fp32 global store deferred)
    #pragma unroll
    for (int nt = 0; nt < 2; ++nt)
        #pragma unroll
        for (int r = 0; r < 4; ++r) {
            int nl = nt * 16 + quad * 4 + r;
            #pragma unroll
            for (int mt = 0; mt < 8; ++mt) {
                int m = Mw + mt * 16 + ln;
                int chunk = m >> 3;
                int addr = nl * 2048 + (((chunk ^ (nl & 7))) << 4) + ((m & 7) << 1);
                *(ushort_t*)&gsm[addr] = f2bf_rne(acc[nt][mt][r]);
            }
        }
    __syncthreads();

    // ---- phase 2: gv[n][c] = sum_m gate[n][m]*v[c][m]; wave owns c-slice w*16
    const ushort_t* vb_h = vB_hi + (size_t)b * CI_ * N_;
    const ushort_t* vb_l = vB_lo + (size_t)b * CI_ * N_;

    f32x4 acc2[2];
    acc2[0] = (f32x4){0.f,0.f,0.f,0.f};
    acc2[1] = (f32x4){0.f,0.f,0.f,0.f};

    #pragma unroll 4
    for (int m0 = 0; m0 < 1024; m0 += 32) {
        v8bf Bg[2];
        #pragma unroll
        for (int nt = 0; nt < 2; ++nt) {
            int nl = nt * 16 + ln;
            int chunk = (m0 >> 3) + quad;
            Bg[nt] = *(const v8bf*)&gsm[nl * 2048 + (((chunk ^ (nl & 7))) << 4)];
        }
        int c = w * 16 + ln;
        size_t aoff = (((size_t)(m0 >> 5)) * 128 + c) * 32 + quad * 8;
        v8bf Avh = ld8(vb_h + aoff);
        v8bf Avl = ld8(vb_l + aoff);
        __builtin_amdgcn_s_setprio(1);
        #pragma unroll
        for (int nt = 0; nt < 2; ++nt) {
            acc2[nt] = __builtin_amdgcn_mfma_f32_16x16x32_bf16(Avh, Bg[nt], acc2[nt], 0, 0, 0);
            acc2[nt] = __builtin_amdgcn_mfma_f32_16x16x32_bf16(Avl, Bg[nt], acc2[nt], 0, 0, 0);
        }
        __builtin_amdgcn_s_setprio(0);
    }

    // gv in [b][n][c] layout, float4 (4 consecutive c per lane)
    #pragma unroll
    for (int nt = 0; nt < 2; ++nt) {
        int n = n0 + nt * 16 + ln;
        float4 o4 = make_float4(acc2[nt][0], acc2[nt][1], acc2[nt][2], acc2[nt][3]);
        *(float4*)&gv[((size_t)(b * N_) + n) * CI_ + w * 16 + quad * 4] = o4;
    }

    // ---- deferred gate fp32 global store
    float* grow = gate + (size_t)b * N_ * N_;
    #pragma unroll
    for (int nt = 0; nt < 2; ++nt)
        #pragma unroll
        for (int r = 0; r < 4; ++r) {
            int n = n0 + nt * 16 + quad * 4 + r;
            #pragma unroll
            for (int mt = 0; mt < 8; ++mt) {
                int m = Mw + mt * 16 + ln;
                grow[(size_t)n * N_ + m] = acc[nt][mt][r];
            }
        }

    // mean partials
    float s0 = acc2[0][0] + acc2[1][0];
    float s1 = acc2[0][1] + acc2[1][1];
    float s2 = acc2[0][2] + acc2[1][2];
    float s3 = acc2[0][3] + acc2[1][3];
    #pragma unroll
    for (int xm = 1; xm <= 8; xm <<= 1) {
        s0 += __shfl_xor(s0, xm, 64);
        s1 += __shfl_xor(s1, xm, 64);
        s2 += __shfl_xor(s2, xm, 64);
        s3 += __shfl_xor(s3, xm, 64);
    }
    if (ln == 0) {
        int cb = b * CI_ + w * 16 + quad * 4;
        atomicAdd(&meanb[cb + 0], s0);
        atomicAdd(&meanb[cb + 1], s1);
        atomicAdd(&meanb[cb + 2], s2);
        atomicAdd(&meanb[cb + 3], s3);
    }
}

// ---------------------------------------------------------------------------
// K3: gv*ca -> bf16 hi/lo split, ONCE. Also computes+writes ca.
__global__ __launch_bounds__(256) void gvca_prep_kernel(
    const float* __restrict__ gv, const float* __restrict__ meanb,
    const float* __restrict__ w1d,
    ushort_t* __restrict__ gvh, ushort_t* __restrict__ gvl,
    float* __restrict__ ca_out)
{
    __shared__ float ca_s[128];
    const int lin = blockIdx.x;
    const int b  = lin & 7;            // XCD pin
    const int ns = lin >> 3;           // 0..31
    const int tid = threadIdx.x;

    if (tid < 128) {
        const float sc = 1.0f / 1024.0f;
        int t = b * 128 + tid;
        float left  = (tid > 0)   ? meanb[t - 1] * sc : 0.0f;
        float mid   = meanb[t] * sc;
        float right = (tid < 127) ? meanb[t + 1] * sc : 0.0f;
        float val = w1d[0] * left + w1d[1] * mid + w1d[2] * right;
        float s = 1.0f / (1.0f + __expf(-val));
        ca_s[tid] = s;
        if (ns == 0) ca_out[t] = s;
    }
    __syncthreads();

    const int cl = (tid & 31) * 4;
    const int nr = tid >> 5;           // 0..7
    #pragma unroll
    for (int i = 0; i < 4; ++i) {
        int n = ns * 32 + nr + i * 8;
        size_t off = ((size_t)(b * N_) + n) * 128 + cl;
        float4 v4 = *(const float4*)&gv[off];
        float vv[4] = { v4.x * ca_s[cl], v4.y * ca_s[cl + 1],
                        v4.z * ca_s[cl + 2], v4.w * ca_s[cl + 3] };
        unsigned int h01 = 0, h23 = 0, l01 = 0, l23 = 0;
        #pragma unroll
        for (int t = 0; t < 4; ++t) {
            unsigned short h = f2bf_rne(vv[t]);
            unsigned short lo = f2bf_rne(vv[t] - bf2f(h));
            if (t < 2) { h01 |= ((unsigned)h) << (16 * t); l01 |= ((unsigned)lo) << (16 * t); }
            else       { h23 |= ((unsigned)h) << (16 * (t - 2)); l23 |= ((unsigned)lo) << (16 * (t - 2)); }
        }
        *(uint2*)&gvh[off] = make_uint2(h01, h23);
        *(uint2*)&gvl[off] = make_uint2(l01, l23);
    }
}

// ---------------------------------------------------------------------------
// K7: MFMA conv, re-tiled: 512 threads, 4 h-rows per block (wx in 0..3),
// 64 o-rows (wy in 0..1). Halves per-output A-panel L2 traffic and barrier
// count. 256 blocks, 85 KB dynamic LDS (1 block/CU, 8 waves = same as the
// previous 2x4-wave config).
#define CV_BHI  0
#define CV_BLO  26112
__global__ __launch_bounds__(512, 1) void conv_mfma_kernel(
    const ushort_t* __restrict__ gvh, const ushort_t* __restrict__ gvl,
    const ushort_t* __restrict__ Whi, const ushort_t* __restrict__ Wlo,
    float* __restrict__ out)
{
    extern __shared__ __align__(16) char smem[];
    const int AH[2] = {52224, 68608};
    const int AL[2] = {60416, 76800};

    const int lin = blockIdx.x;
    const int b    = lin & 7;          // XCD pin
    const int rest = lin >> 3;         // 0..31
    const int o0 = (rest & 3) * 64;
    const int h0 = (rest >> 2) * 4;
    const int tid = threadIdx.x;
    const int l   = tid & 63;
    const int wv  = tid >> 6;          // 0..7
    const int wy  = wv >> 2;           // 0..1 : o-subrange
    const int wx  = wv & 3;            // 0..3 : h-row
    const int ln  = l & 15;
    const int quad = l >> 4;

    f32x4 acc[2][2];
    #pragma unroll
    for (int i = 0; i < 2; ++i)
        #pragma unroll
        for (int j = 0; j < 2; ++j)
            acc[i][j] = (f32x4){0.f, 0.f, 0.f, 0.f};

    const int srow = tid >> 3, scol = tid & 7;   // A-stage: 64 rows x 8 slots
    const int la   = srow * 128 + scol * 16;
    const int csrc = scol ^ (srow & 7);

    for (int half = 0; half < 2; ++half) {
        __syncthreads();   // previous half fully consumed
        // ---- stage B: 6 h-rows x 34 cols halo tile of pre-split gv*ca
        for (int u = tid; u < 204 * 8; u += 512) {
            int p  = u >> 3;
            int cs = u & 7;
            int hrel = p / 34;
            int c    = p - hrel * 34;
            int gr = h0 + hrel - 1;
            int gc = c - 1;
            bool ok = ((unsigned)gr < 32u) && ((unsigned)gc < 32u);
            uint4 h4 = make_uint4(0, 0, 0, 0), l4 = make_uint4(0, 0, 0, 0);
            if (ok) {
                size_t src = ((size_t)(b * N_) + gr * 32 + gc) * 128 + half * 64 + cs * 8;
                h4 = *(const uint4*)&gvh[src];
                l4 = *(const uint4*)&gvl[src];
            }
            int addr = p * 128 + ((cs ^ (p & 7)) << 4);
            *(uint4*)&smem[CV_BHI + addr] = h4;
            *(uint4*)&smem[CV_BLO + addr] = l4;
        }
        // ---- preload A(tap=0) into buffer 0 (1 slot per thread)
        {
            size_t g = (size_t)(o0 + srow) * 1152 + half * 64 + csrc * 8;
            *(uint4*)&smem[AH[0] + la] = *(const uint4*)&Whi[g];
            *(uint4*)&smem[AL[0] + la] = *(const uint4*)&Wlo[g];
        }

        for (int tap = 0; tap < 9; ++tap) {
            __syncthreads();   // buf[tap&1] + B ready; buf[(tap+1)&1] free
            uint4 nh, nl;
            if (tap < 8) {
                size_t g = (size_t)(o0 + srow) * 1152 + (tap + 1) * 128 + half * 64 + csrc * 8;
                nh = *(const uint4*)&Whi[g];
                nl = *(const uint4*)&Wlo[g];
            }
            const int ah = AH[tap & 1], al = AL[tap & 1];
            const int dy = tap / 3, dx = tap - dy * 3;
            const int pbase = (wx + dy) * 34 + dx;
            #pragma unroll
            for (int cc = 0; cc < 2; ++cc) {
                v8bf Bh[2], Bl[2], Ah2[2], Al2[2];
                #pragma unroll
                for (int j = 0; j < 2; ++j) {
                    int p = pbase + j * 16 + ln;
                    int ch = cc * 4 + quad;
                    int addr = p * 128 + ((ch ^ (p & 7)) << 4);
                    Bh[j] = *(const v8bf*)&smem[CV_BHI + addr];
                    Bl[j] = *(const v8bf*)&smem[CV_BLO + addr];
                }
                #pragma unroll
                for (int i = 0; i < 2; ++i) {
                    int o = wy * 32 + i * 16 + ln;
                    int ch = cc * 4 + quad;
                    int addr = o * 128 + ((ch ^ (o & 7)) << 4);
                    Ah2[i] = *(const v8bf*)&smem[ah + addr];
                    Al2[i] = *(const v8bf*)&smem[al + addr];
                }
                __builtin_amdgcn_s_setprio(1);
                #pragma unroll
                for (int i = 0; i < 2; ++i)
                    #pragma unroll
                    for (int j = 0; j < 2; ++j) {
                        acc[i][j] = __builtin_amdgcn_mfma_f32_16x16x32_bf16(Ah2[i], Bh[j], acc[i][j], 0, 0, 0);
                        acc[i][j] = __builtin_amdgcn_mfma_f32_16x16x32_bf16(Ah2[i], Bl[j], acc[i][j], 0, 0, 0);
                        acc[i][j] = __builtin_amdgcn_mfma_f32_16x16x32_bf16(Al2[i], Bh[j], acc[i][j], 0, 0, 0);
                    }
                __builtin_amdgcn_s_setprio(0);
            }
            if (tap < 8) {
                int nb = (tap + 1) & 1;
                *(uint4*)&smem[AH[nb] + la] = nh;
                *(uint4*)&smem[AL[nb] + la] = nl;
            }
        }
    }

    const int h = h0 + wx;
    #pragma unroll
    for (int i = 0; i < 2; ++i)
        #pragma unroll
        for (int j = 0; j < 2; ++j)
            #pragma unroll
            for (int r = 0; r < 4; ++r) {
                int o = o0 + wy * 32 + i * 16 + quad * 4 + r;
                int w = j * 16 + ln;
                out[(size_t)(b * CO_ + o) * N_ + h * 32 + w] = acc[i][j][r];
            }
}

// ---------------------------------------------------------------------------
extern "C" void kernel_launch(void* const* d_in, const int* in_sizes, int n_in,
                              void* d_out, int out_size, void* d_ws, size_t ws_size,
                              hipStream_t stream) {
    const float* x   = (const float*)d_in[0];
    const float* Wq  = (const float*)d_in[1];
    const float* Wk  = (const float*)d_in[2];
    const float* Wv  = (const float*)d_in[3];
    const float* w1d = (const float*)d_in[4];
    const float* Wc  = (const float*)d_in[5];

    float* out  = (float*)d_out;
    float* gate = out + 2097152;
    float* ca   = gate + 8388608;

    float*    gv      = (float*)d_ws;            // 1048576 f  [b][n][c] layout
    float*    meanb   = gv + 1048576;            // 1024 f (sum over n)
    ushort_t* Whi     = (ushort_t*)(meanb + 1024);   // 294912
    ushort_t* Wlo     = Whi + 294912;
    ushort_t* Wp_hi   = Wlo + 294912;            // 98304
    ushort_t* Wp_lo   = Wp_hi + 98304;
    ushort_t* xs_hi   = Wp_lo + 98304;           // 2097152
    ushort_t* xs_lo   = xs_hi + 2097152;
    ushort_t* qt_hi   = xs_lo + 2097152;         // 1048576
    ushort_t* qt_lo   = qt_hi + 1048576;
    ushort_t* kt_hi   = qt_lo + 1048576;
    ushort_t* kt_lo   = kt_hi + 1048576;
    ushort_t* vB_hi   = kt_lo + 1048576;         // 1048576 (packed [b][m>>5][c][m&31])
    ushort_t* vB_lo   = vB_hi + 1048576;
    ushort_t* gvh     = vB_lo + 1048576;         // 1048576 ([b][n][c], gv*ca hi)
    ushort_t* gvl     = gvh + 1048576;

    static bool s_attr_done = false;
    if (!s_attr_done) {
        hipFuncSetAttribute((const void*)conv_mfma_kernel,
                            hipFuncAttributeMaxDynamicSharedMemorySize, 84992);
        s_attr_done = true;
    }

    prep_all_kernel<<<dim3(2560), 256, 0, stream>>>(
        x, Wc, Wq, Wk, Wv, Whi, Wlo, Wp_hi, Wp_lo, xs_hi, xs_lo, meanb);
    proj_mfma_kernel<<<dim3(16, 6, 8), 256, 0, stream>>>(
        Wp_hi, Wp_lo, xs_hi, xs_lo, qt_hi, qt_lo, kt_hi, kt_lo, vB_hi, vB_lo);
    attn_fused_kernel<<<dim3(32, 8), 512, 0, stream>>>(
        qt_hi, qt_lo, kt_hi, kt_lo, vB_hi, vB_lo, gate, gv, meanb);
    gvca_prep_kernel<<<dim3(256), 256, 0, stream>>>(
        gv, meanb, w1d, gvh, gvl, ca);
    conv_mfma_kernel<<<dim3(256), 512, 84992, stream>>>(
        gvh, gvl, Whi, Wlo, out);
}

// Round 7
// 275.300 us; speedup vs baseline: 1.0088x; 1.0088x over previous
//
#include <hip/hip_runtime.h>
#include <math.h>

#define B_   8
#define C_   256
#define CI_  128
#define N_   1024
#define HW_  32
#define CO_  256

typedef __bf16 v8bf __attribute__((ext_vector_type(8)));
typedef float  f32x4 __attribute__((ext_vector_type(4)));
typedef unsigned short ushort_t;

__device__ __forceinline__ unsigned short f2bf_rne(float f) {
    unsigned int u = __float_as_uint(f);
    unsigned int r = u + 0x7FFF + ((u >> 16) & 1);
    return (unsigned short)(r >> 16);
}
__device__ __forceinline__ float bf2f(unsigned short h) {
    return __uint_as_float(((unsigned int)h) << 16);
}
__device__ __forceinline__ v8bf ld8(const ushort_t* p) {
    return *(const v8bf*)p;
}

// ---------------------------------------------------------------------------
// P1 (merged): blocks [0,1152) split Wc; [1152,1536) split Wq/Wk/Wv;
// [1536,2560) gather strided x -> xs_t[b][n][c] bf16 hi/lo.
__global__ __launch_bounds__(256) void prep_all_kernel(
    const float* __restrict__ x,
    const float* __restrict__ Wc,
    const float* __restrict__ Wq, const float* __restrict__ Wk,
    const float* __restrict__ Wv,
    ushort_t* __restrict__ Whi, ushort_t* __restrict__ Wlo,
    ushort_t* __restrict__ Wp_hi, ushort_t* __restrict__ Wp_lo,
    ushort_t* __restrict__ xs_hi, ushort_t* __restrict__ xs_lo,
    float* __restrict__ meanb)
{
    __shared__ ushort_t lh[32 * 72];
    __shared__ ushort_t ll[32 * 72];
    const int bx = blockIdx.x;
    const int tid = threadIdx.x;

    if (bx < 1152) {
        if (bx == 0) {   // zero the mean accumulator (1024 floats)
            *(float4*)&meanb[tid * 4] = make_float4(0.f, 0.f, 0.f, 0.f);
        }
        int idx = bx * 256 + tid;                 // 294912
        int o = idx / 1152;
        int r = idx - o * 1152;
        int ci = r / 9;
        int tap = r - ci * 9;
        float v = Wc[idx];
        unsigned short h = f2bf_rne(v);
        unsigned short l = f2bf_rne(v - bf2f(h));
        int didx = o * 1152 + tap * 128 + ci;
        Whi[didx] = h; Wlo[didx] = l;
    } else if (bx < 1536) {
        int j = (bx - 1152) * 256 + tid;          // 98304
        int o = j >> 8, c = j & 255;
        float v = (o < 128) ? Wq[o * 256 + c]
                : (o < 256) ? Wk[(o - 128) * 256 + c]
                            : Wv[(o - 256) * 256 + c];
        unsigned short h = f2bf_rne(v);
        unsigned short l = f2bf_rne(v - bf2f(h));
        Wp_hi[j] = h; Wp_lo[j] = l;
    } else {
        const int bx2 = bx - 1536;                // 1024 blocks: b(8) x h(32) x cq(4)
        const int cq = bx2 & 3;
        const int h  = (bx2 >> 2) & 31;
        const int b  = bx2 >> 7;
        const int w = tid & 31, cg = tid >> 5;
        const float4* xrow = (const float4*)x;
        float v[8];
        #pragma unroll
        for (int i = 0; i < 8; ++i) {
            int c = cq * 64 + i * 8 + cg;
            // element (b,c,h*4,w*4) = float4 index ((b*C_+c)*4096 + h*128 + w).x
            v[i] = xrow[(size_t)(b * C_ + c) * 4096 + h * 128 + w].x;
        }
        #pragma unroll
        for (int i = 0; i < 8; ++i) {
            int cl = i * 8 + cg;
            unsigned short hi = f2bf_rne(v[i]);
            unsigned short lo = f2bf_rne(v[i] - bf2f(hi));
            lh[w * 72 + cl] = hi;
            ll[w * 72 + cl] = lo;
        }
        __syncthreads();
        const int ww = tid >> 3, cs = tid & 7;
        size_t dst = ((size_t)(b * N_) + h * 32 + ww) * 256 + cq * 64 + cs * 8;
        *(uint4*)&xs_hi[dst] = *(uint4*)&lh[ww * 72 + cs * 8];
        *(uint4*)&xs_lo[dst] = *(uint4*)&ll[ww * 72 + cs * 8];
    }
}

// ---------------------------------------------------------------------------
// K1: proj MFMA. A = Wp [o][c] hi/lo, B = xs_t [n][c] hi/lo. 3-term split.
// XCD-pinned (batch = lin&7). V-blocks use operand-swapped MFMA (same product
// set) so the register dim = m -> vectorized uint2 vB stores.
__global__ __launch_bounds__(256) void proj_mfma_kernel(
    const ushort_t* __restrict__ Wp_hi, const ushort_t* __restrict__ Wp_lo,
    const ushort_t* __restrict__ xs_hi, const ushort_t* __restrict__ xs_lo,
    ushort_t* __restrict__ qt_hi, ushort_t* __restrict__ qt_lo,
    ushort_t* __restrict__ kt_hi, ushort_t* __restrict__ kt_lo,
    ushort_t* __restrict__ vB_hi, ushort_t* __restrict__ vB_lo)
{
    const int lin = blockIdx.x + 16 * (blockIdx.y + 6 * blockIdx.z);
    const int b    = lin & 7;          // XCD pin
    const int rest = lin >> 3;         // 0..95
    const int n0 = (rest & 15) * 64;
    const int o0 = (rest >> 4) * 64;
    const int tid = threadIdx.x;
    const int l = tid & 63, wv = tid >> 6;
    const int wy = wv >> 1, wx = wv & 1;
    const int ln = l & 15, quad = l >> 4;

    const ushort_t* Ah_p[2]; const ushort_t* Al_p[2];
    const ushort_t* Bh_p[2]; const ushort_t* Bl_p[2];
    #pragma unroll
    for (int i = 0; i < 2; ++i) {
        size_t off = (size_t)(o0 + wy * 32 + i * 16 + ln) * 256 + quad * 8;
        Ah_p[i] = Wp_hi + off; Al_p[i] = Wp_lo + off;
    }
    #pragma unroll
    for (int j = 0; j < 2; ++j) {
        size_t off = ((size_t)(b * N_) + n0 + wx * 32 + j * 16 + ln) * 256 + quad * 8;
        Bh_p[j] = xs_hi + off; Bl_p[j] = xs_lo + off;
    }

    f32x4 acc[2][2];
    #pragma unroll
    for (int i = 0; i < 2; ++i)
        #pragma unroll
        for (int j = 0; j < 2; ++j) acc[i][j] = (f32x4){0.f,0.f,0.f,0.f};

    if (o0 < 256) {
        #pragma unroll 4
        for (int k0 = 0; k0 < 256; k0 += 32) {
            v8bf Ah[2], Al[2], Bh[2], Bl[2];
            #pragma unroll
            for (int i = 0; i < 2; ++i) { Ah[i] = ld8(Ah_p[i] + k0); Al[i] = ld8(Al_p[i] + k0); }
            #pragma unroll
            for (int j = 0; j < 2; ++j) { Bh[j] = ld8(Bh_p[j] + k0); Bl[j] = ld8(Bl_p[j] + k0); }
            __builtin_amdgcn_s_setprio(1);
            #pragma unroll
            for (int i = 0; i < 2; ++i)
                #pragma unroll
                for (int j = 0; j < 2; ++j) {
                    acc[i][j] = __builtin_amdgcn_mfma_f32_16x16x32_bf16(Ah[i], Bh[j], acc[i][j], 0, 0, 0);
                    acc[i][j] = __builtin_amdgcn_mfma_f32_16x16x32_bf16(Ah[i], Bl[j], acc[i][j], 0, 0, 0);
                    acc[i][j] = __builtin_amdgcn_mfma_f32_16x16x32_bf16(Al[i], Bh[j], acc[i][j], 0, 0, 0);
                }
            __builtin_amdgcn_s_setprio(0);
        }
        // q or k: transposed store [n][o], pack 4 consecutive o (regs) into 8B
        ushort_t* th = (o0 < 128) ? qt_hi : kt_hi;
        ushort_t* tl = (o0 < 128) ? qt_lo : kt_lo;
        const int ob = o0 & 127;
        #pragma unroll
        for (int i = 0; i < 2; ++i)
            #pragma unroll
            for (int j = 0; j < 2; ++j) {
                int oo = ob + wy * 32 + i * 16 + quad * 4;
                int n  = n0 + wx * 32 + j * 16 + ln;
                unsigned int h01 = 0, h23 = 0, l01 = 0, l23 = 0;
                #pragma unroll
                for (int r = 0; r < 4; ++r) {
                    float f = acc[i][j][r];
                    unsigned short hh = f2bf_rne(f);
                    unsigned short lo = f2bf_rne(f - bf2f(hh));
                    if (r < 2) { h01 |= ((unsigned)hh) << (16 * r); l01 |= ((unsigned)lo) << (16 * r); }
                    else       { h23 |= ((unsigned)hh) << (16 * (r - 2)); l23 |= ((unsigned)lo) << (16 * (r - 2)); }
                }
                size_t off = ((size_t)(b * N_) + n) * 128 + oo;
                *(uint2*)&th[off] = make_uint2(h01, h23);
                *(uint2*)&tl[off] = make_uint2(l01, l23);
            }
    } else {
        // v: operand-swapped -> acc[j][i] rows = m, cols = c
        #pragma unroll 4
        for (int k0 = 0; k0 < 256; k0 += 32) {
            v8bf Ah[2], Al[2], Bh[2], Bl[2];
            #pragma unroll
            for (int i = 0; i < 2; ++i) { Ah[i] = ld8(Ah_p[i] + k0); Al[i] = ld8(Al_p[i] + k0); }
            #pragma unroll
            for (int j = 0; j < 2; ++j) { Bh[j] = ld8(Bh_p[j] + k0); Bl[j] = ld8(Bl_p[j] + k0); }
            __builtin_amdgcn_s_setprio(1);
            #pragma unroll
            for (int j = 0; j < 2; ++j)
                #pragma unroll
                for (int i = 0; i < 2; ++i) {
                    acc[j][i] = __builtin_amdgcn_mfma_f32_16x16x32_bf16(Bh[j], Ah[i], acc[j][i], 0, 0, 0);
                    acc[j][i] = __builtin_amdgcn_mfma_f32_16x16x32_bf16(Bh[j], Al[i], acc[j][i], 0, 0, 0);
                    acc[j][i] = __builtin_amdgcn_mfma_f32_16x16x32_bf16(Bl[j], Ah[i], acc[j][i], 0, 0, 0);
                }
            __builtin_amdgcn_s_setprio(0);
        }
        // vB[b][m>>5][c][m&31]; reg dim = m (4 consecutive) -> uint2 stores
        const int mhi = (n0 >> 5) + wx;
        #pragma unroll
        for (int j = 0; j < 2; ++j)
            #pragma unroll
            for (int i = 0; i < 2; ++i) {
                int c   = (o0 - 256) + wy * 32 + i * 16 + ln;
                int mlo = j * 16 + quad * 4;
                unsigned int h01 = 0, h23 = 0, l01 = 0, l23 = 0;
                #pragma unroll
                for (int r = 0; r < 4; ++r) {
                    float f = acc[j][i][r];
                    unsigned short hh = f2bf_rne(f);
                    unsigned short lo = f2bf_rne(f - bf2f(hh));
                    if (r < 2) { h01 |= ((unsigned)hh) << (16 * r); l01 |= ((unsigned)lo) << (16 * r); }
                    else       { h23 |= ((unsigned)hh) << (16 * (r - 2)); l23 |= ((unsigned)lo) << (16 * (r - 2)); }
                }
                size_t off = (((size_t)b * 32 + mhi) * 128 + c) * 32 + mlo;
                *(uint2*)&vB_hi[off] = make_uint2(h01, h23);
                *(uint2*)&vB_lo[off] = make_uint2(l01, l23);
            }
    }
}

// ---------------------------------------------------------------------------
// K2: fused attention, 512 threads / 8 waves, XCD-pinned. Gate fp32 store
// deferred past phase 2. Accumulates mean partials (atomicAdd).
__global__ __launch_bounds__(512, 2) void attn_fused_kernel(
    const ushort_t* __restrict__ qt_hi, const ushort_t* __restrict__ qt_lo,
    const ushort_t* __restrict__ kt_hi, const ushort_t* __restrict__ kt_lo,
    const ushort_t* __restrict__ vB_hi, const ushort_t* __restrict__ vB_lo,
    float* __restrict__ gate, float* __restrict__ gv, float* __restrict__ meanb)
{
    __shared__ __align__(16) char gsm[65536];     // Gbf[32][1024] bf16, swizzled
    __shared__ float redA[8][32];
    __shared__ float redB[8][32];

    const int lin = blockIdx.x + 32 * blockIdx.y;
    const int b  = lin & 7;            // XCD pin
    const int n0 = (lin >> 3) * 32;
    const int tid = threadIdx.x;
    const int l = tid & 63, w = tid >> 6;         // w in [0,8)
    const int ln = l & 15, quad = l >> 4;
    const int Mw = w * 128;

    const ushort_t* qb_h = qt_hi + ((size_t)(b * N_) + n0) * 128;
    const ushort_t* qb_l = qt_lo + ((size_t)(b * N_) + n0) * 128;
    const ushort_t* kb_h = kt_hi + (size_t)(b * N_) * 128;
    const ushort_t* kb_l = kt_lo + (size_t)(b * N_) * 128;

    f32x4 acc[2][8];
    #pragma unroll
    for (int nt = 0; nt < 2; ++nt)
        #pragma unroll
        for (int mt = 0; mt < 8; ++mt) acc[nt][mt] = (f32x4){0.f,0.f,0.f,0.f};

    // ---- phase 1: scores (3-term bf16 split)
    #pragma unroll
    for (int c0 = 0; c0 < 128; c0 += 32) {
        v8bf Ah[2], Al[2];
        #pragma unroll
        for (int nt = 0; nt < 2; ++nt) {
            size_t aoff = (size_t)(nt * 16 + ln) * 128 + c0 + quad * 8;
            Ah[nt] = ld8(qb_h + aoff); Al[nt] = ld8(qb_l + aoff);
        }
        #pragma unroll
        for (int mt = 0; mt < 8; ++mt) {
            size_t boff = (size_t)(Mw + mt * 16 + ln) * 128 + c0 + quad * 8;
            v8bf Bh = ld8(kb_h + boff);
            v8bf Bl = ld8(kb_l + boff);
            __builtin_amdgcn_s_setprio(1);
            #pragma unroll
            for (int nt = 0; nt < 2; ++nt) {
                acc[nt][mt] = __builtin_amdgcn_mfma_f32_16x16x32_bf16(Ah[nt], Bh, acc[nt][mt], 0, 0, 0);
                acc[nt][mt] = __builtin_amdgcn_mfma_f32_16x16x32_bf16(Ah[nt], Bl, acc[nt][mt], 0, 0, 0);
                acc[nt][mt] = __builtin_amdgcn_mfma_f32_16x16x32_bf16(Al[nt], Bh, acc[nt][mt], 0, 0, 0);
            }
            __builtin_amdgcn_s_setprio(0);
        }
    }

    // ---- softmax
    float rmax[2][4];
    #pragma unroll
    for (int nt = 0; nt < 2; ++nt)
        #pragma unroll
        for (int r = 0; r < 4; ++r) {
            float m = acc[nt][0][r];
            #pragma unroll
            for (int mt = 1; mt < 8; ++mt) m = fmaxf(m, acc[nt][mt][r]);
            rmax[nt][r] = m;
        }
    #pragma unroll
    for (int nt = 0; nt < 2; ++nt)
        #pragma unroll
        for (int r = 0; r < 4; ++r) {
            float m = rmax[nt][r];
            #pragma unroll
            for (int xm = 1; xm <= 8; xm <<= 1) m = fmaxf(m, __shfl_xor(m, xm, 64));
            rmax[nt][r] = m;
        }
    if (ln == 0) {
        #pragma unroll
        for (int nt = 0; nt < 2; ++nt)
            #pragma unroll
            for (int r = 0; r < 4; ++r)
                redA[w][nt * 16 + quad * 4 + r] = rmax[nt][r];
    }
    __syncthreads();
    #pragma unroll
    for (int nt = 0; nt < 2; ++nt)
        #pragma unroll
        for (int r = 0; r < 4; ++r) {
            int row = nt * 16 + quad * 4 + r;
            float m0 = fmaxf(fmaxf(redA[0][row], redA[1][row]),
                             fmaxf(redA[2][row], redA[3][row]));
            float m1 = fmaxf(fmaxf(redA[4][row], redA[5][row]),
                             fmaxf(redA[6][row], redA[7][row]));
            rmax[nt][r] = fmaxf(m0, m1);
        }

    float rsum[2][4];
    #pragma unroll
    for (int nt = 0; nt < 2; ++nt)
        #pragma unroll
        for (int r = 0; r < 4; ++r) {
            float s = 0.f;
            #pragma unroll
            for (int mt = 0; mt < 8; ++mt) {
                float e = __expf(acc[nt][mt][r] - rmax[nt][r]);
                acc[nt][mt][r] = e;
                s += e;
            }
            rsum[nt][r] = s;
        }
    #pragma unroll
    for (int nt = 0; nt < 2; ++nt)
        #pragma unroll
        for (int r = 0; r < 4; ++r) {
            float s = rsum[nt][r];
            #pragma unroll
            for (int xm = 1; xm <= 8; xm <<= 1) s += __shfl_xor(s, xm, 64);
            rsum[nt][r] = s;
        }
    if (ln == 0) {
        #pragma unroll
        for (int nt = 0; nt < 2; ++nt)
            #pragma unroll
            for (int r = 0; r < 4; ++r)
                redB[w][nt * 16 + quad * 4 + r] = rsum[nt][r];
    }
    __syncthreads();
    #pragma unroll
    for (int nt = 0; nt < 2; ++nt)
        #pragma unroll
        for (int r = 0; r < 4; ++r) {
            int row = nt * 16 + quad * 4 + r;
            float inv = 1.0f / ((redB[0][row] + redB[1][row] + redB[2][row] + redB[3][row]) +
                                (redB[4][row] + redB[5][row] + redB[6][row] + redB[7][row]));
            #pragma unroll
            for (int mt = 0; mt < 8; ++mt) acc[nt][mt][r] *= inv;
        }

    // ---- write gate bf16 -> swizzled LDS only (fp32 global store deferred)
    #pragma unroll
    for (int nt = 0; nt < 2; ++nt)
        #pragma unroll
        for (int r = 0; r < 4; ++r) {
            int nl = nt * 16 + quad * 4 + r;
            #pragma unroll
            for (int mt = 0; mt < 8; ++mt) {
                int m = Mw + mt * 16 + ln;
                int chunk = m >> 3;
                int addr = nl * 2048 + (((chunk ^ (nl & 7))) << 4) + ((m & 7) << 1);
                *(ushort_t*)&gsm[addr] = f2bf_rne(acc[nt][mt][r]);
            }
        }
    __syncthreads();

    // ---- phase 2: gv[n][c] = sum_m gate[n][m]*v[c][m]; wave owns c-slice w*16
    const ushort_t* vb_h = vB_hi + (size_t)b * CI_ * N_;
    const ushort_t* vb_l = vB_lo + (size_t)b * CI_ * N_;

    f32x4 acc2[2];
    acc2[0] = (f32x4){0.f,0.f,0.f,0.f};
    acc2[1] = (f32x4){0.f,0.f,0.f,0.f};

    #pragma unroll 4
    for (int m0 = 0; m0 < 1024; m0 += 32) {
        v8bf Bg[2];
        #pragma unroll
        for (int nt = 0; nt < 2; ++nt) {
            int nl = nt * 16 + ln;
            int chunk = (m0 >> 3) + quad;
            Bg[nt] = *(const v8bf*)&gsm[nl * 2048 + (((chunk ^ (nl & 7))) << 4)];
        }
        int c = w * 16 + ln;
        size_t aoff = (((size_t)(m0 >> 5)) * 128 + c) * 32 + quad * 8;
        v8bf Avh = ld8(vb_h + aoff);
        v8bf Avl = ld8(vb_l + aoff);
        __builtin_amdgcn_s_setprio(1);
        #pragma unroll
        for (int nt = 0; nt < 2; ++nt) {
            acc2[nt] = __builtin_amdgcn_mfma_f32_16x16x32_bf16(Avh, Bg[nt], acc2[nt], 0, 0, 0);
            acc2[nt] = __builtin_amdgcn_mfma_f32_16x16x32_bf16(Avl, Bg[nt], acc2[nt], 0, 0, 0);
        }
        __builtin_amdgcn_s_setprio(0);
    }

    // gv in [b][n][c] layout, float4 (4 consecutive c per lane)
    #pragma unroll
    for (int nt = 0; nt < 2; ++nt) {
        int n = n0 + nt * 16 + ln;
        float4 o4 = make_float4(acc2[nt][0], acc2[nt][1], acc2[nt][2], acc2[nt][3]);
        *(float4*)&gv[((size_t)(b * N_) + n) * CI_ + w * 16 + quad * 4] = o4;
    }

    // ---- deferred gate fp32 global store
    float* grow = gate + (size_t)b * N_ * N_;
    #pragma unroll
    for (int nt = 0; nt < 2; ++nt)
        #pragma unroll
        for (int r = 0; r < 4; ++r) {
            int n = n0 + nt * 16 + quad * 4 + r;
            #pragma unroll
            for (int mt = 0; mt < 8; ++mt) {
                int m = Mw + mt * 16 + ln;
                grow[(size_t)n * N_ + m] = acc[nt][mt][r];
            }
        }

    // mean partials
    float s0 = acc2[0][0] + acc2[1][0];
    float s1 = acc2[0][1] + acc2[1][1];
    float s2 = acc2[0][2] + acc2[1][2];
    float s3 = acc2[0][3] + acc2[1][3];
    #pragma unroll
    for (int xm = 1; xm <= 8; xm <<= 1) {
        s0 += __shfl_xor(s0, xm, 64);
        s1 += __shfl_xor(s1, xm, 64);
        s2 += __shfl_xor(s2, xm, 64);
        s3 += __shfl_xor(s3, xm, 64);
    }
    if (ln == 0) {
        int cb = b * CI_ + w * 16 + quad * 4;
        atomicAdd(&meanb[cb + 0], s0);
        atomicAdd(&meanb[cb + 1], s1);
        atomicAdd(&meanb[cb + 2], s2);
        atomicAdd(&meanb[cb + 3], s3);
    }
}

// ---------------------------------------------------------------------------
// K3: gv*ca -> bf16 hi/lo split, ONCE. Also computes+writes ca.
__global__ __launch_bounds__(256) void gvca_prep_kernel(
    const float* __restrict__ gv, const float* __restrict__ meanb,
    const float* __restrict__ w1d,
    ushort_t* __restrict__ gvh, ushort_t* __restrict__ gvl,
    float* __restrict__ ca_out)
{
    __shared__ float ca_s[128];
    const int lin = blockIdx.x;
    const int b  = lin & 7;            // XCD pin
    const int ns = lin >> 3;           // 0..31
    const int tid = threadIdx.x;

    if (tid < 128) {
        const float sc = 1.0f / 1024.0f;
        int t = b * 128 + tid;
        float left  = (tid > 0)   ? meanb[t - 1] * sc : 0.0f;
        float mid   = meanb[t] * sc;
        float right = (tid < 127) ? meanb[t + 1] * sc : 0.0f;
        float val = w1d[0] * left + w1d[1] * mid + w1d[2] * right;
        float s = 1.0f / (1.0f + __expf(-val));
        ca_s[tid] = s;
        if (ns == 0) ca_out[t] = s;
    }
    __syncthreads();

    const int cl = (tid & 31) * 4;
    const int nr = tid >> 5;           // 0..7
    #pragma unroll
    for (int i = 0; i < 4; ++i) {
        int n = ns * 32 + nr + i * 8;
        size_t off = ((size_t)(b * N_) + n) * 128 + cl;
        float4 v4 = *(const float4*)&gv[off];
        float vv[4] = { v4.x * ca_s[cl], v4.y * ca_s[cl + 1],
                        v4.z * ca_s[cl + 2], v4.w * ca_s[cl + 3] };
        unsigned int h01 = 0, h23 = 0, l01 = 0, l23 = 0;
        #pragma unroll
        for (int t = 0; t < 4; ++t) {
            unsigned short h = f2bf_rne(vv[t]);
            unsigned short lo = f2bf_rne(vv[t] - bf2f(h));
            if (t < 2) { h01 |= ((unsigned)h) << (16 * t); l01 |= ((unsigned)lo) << (16 * t); }
            else       { h23 |= ((unsigned)h) << (16 * (t - 2)); l23 |= ((unsigned)lo) << (16 * (t - 2)); }
        }
        *(uint2*)&gvh[off] = make_uint2(h01, h23);
        *(uint2*)&gvl[off] = make_uint2(l01, l23);
    }
}

// ---------------------------------------------------------------------------
// K7: MFMA conv, re-tiled: 512 threads, 4 h-rows per block (wx in 0..3),
// 64 o-rows (wy in 0..1). 256 blocks, 85 KB dynamic LDS.
#define CV_BHI  0
#define CV_BLO  26112
__global__ __launch_bounds__(512, 1) void conv_mfma_kernel(
    const ushort_t* __restrict__ gvh, const ushort_t* __restrict__ gvl,
    const ushort_t* __restrict__ Whi, const ushort_t* __restrict__ Wlo,
    float* __restrict__ out)
{
    extern __shared__ __align__(16) char smem[];
    const int AH[2] = {52224, 68608};
    const int AL[2] = {60416, 76800};

    const int lin = blockIdx.x;
    const int b    = lin & 7;          // XCD pin
    const int rest = lin >> 3;         // 0..31
    const int o0 = (rest & 3) * 64;
    const int h0 = (rest >> 2) * 4;
    const int tid = threadIdx.x;
    const int l   = tid & 63;
    const int wv  = tid >> 6;          // 0..7
    const int wy  = wv >> 2;           // 0..1 : o-subrange
    const int wx  = wv & 3;            // 0..3 : h-row
    const int ln  = l & 15;
    const int quad = l >> 4;

    f32x4 acc[2][2];
    #pragma unroll
    for (int i = 0; i < 2; ++i)
        #pragma unroll
        for (int j = 0; j < 2; ++j)
            acc[i][j] = (f32x4){0.f, 0.f, 0.f, 0.f};

    const int srow = tid >> 3, scol = tid & 7;   // A-stage: 64 rows x 8 slots
    const int la   = srow * 128 + scol * 16;
    const int csrc = scol ^ (srow & 7);

    for (int half = 0; half < 2; ++half) {
        __syncthreads();   // previous half fully consumed
        // ---- stage B: 6 h-rows x 34 cols halo tile of pre-split gv*ca
        for (int u = tid; u < 204 * 8; u += 512) {
            int p  = u >> 3;
            int cs = u & 7;
            int hrel = p / 34;
            int c    = p - hrel * 34;
            int gr = h0 + hrel - 1;
            int gc = c - 1;
            bool ok = ((unsigned)gr < 32u) && ((unsigned)gc < 32u);
            uint4 h4 = make_uint4(0, 0, 0, 0), l4 = make_uint4(0, 0, 0, 0);
            if (ok) {
                size_t src = ((size_t)(b * N_) + gr * 32 + gc) * 128 + half * 64 + cs * 8;
                h4 = *(const uint4*)&gvh[src];
                l4 = *(const uint4*)&gvl[src];
            }
            int addr = p * 128 + ((cs ^ (p & 7)) << 4);
            *(uint4*)&smem[CV_BHI + addr] = h4;
            *(uint4*)&smem[CV_BLO + addr] = l4;
        }
        // ---- preload A(tap=0) into buffer 0 (1 slot per thread)
        {
            size_t g = (size_t)(o0 + srow) * 1152 + half * 64 + csrc * 8;
            *(uint4*)&smem[AH[0] + la] = *(const uint4*)&Whi[g];
            *(uint4*)&smem[AL[0] + la] = *(const uint4*)&Wlo[g];
        }

        for (int tap = 0; tap < 9; ++tap) {
            __syncthreads();   // buf[tap&1] + B ready; buf[(tap+1)&1] free
            uint4 nh, nl;
            if (tap < 8) {
                size_t g = (size_t)(o0 + srow) * 1152 + (tap + 1) * 128 + half * 64 + csrc * 8;
                nh = *(const uint4*)&Whi[g];
                nl = *(const uint4*)&Wlo[g];
            }
            const int ah = AH[tap & 1], al = AL[tap & 1];
            const int dy = tap / 3, dx = tap - dy * 3;
            const int pbase = (wx + dy) * 34 + dx;
            #pragma unroll
            for (int cc = 0; cc < 2; ++cc) {
                v8bf Bh[2], Bl[2], Ah2[2], Al2[2];
                #pragma unroll
                for (int j = 0; j < 2; ++j) {
                    int p = pbase + j * 16 + ln;
                    int ch = cc * 4 + quad;
                    int addr = p * 128 + ((ch ^ (p & 7)) << 4);
                    Bh[j] = *(const v8bf*)&smem[CV_BHI + addr];
                    Bl[j] = *(const v8bf*)&smem[CV_BLO + addr];
                }
                #pragma unroll
                for (int i = 0; i < 2; ++i) {
                    int o = wy * 32 + i * 16 + ln;
                    int ch = cc * 4 + quad;
                    int addr = o * 128 + ((ch ^ (o & 7)) << 4);
                    Ah2[i] = *(const v8bf*)&smem[ah + addr];
                    Al2[i] = *(const v8bf*)&smem[al + addr];
                }
                __builtin_amdgcn_s_setprio(1);
                #pragma unroll
                for (int i = 0; i < 2; ++i)
                    #pragma unroll
                    for (int j = 0; j < 2; ++j) {
                        acc[i][j] = __builtin_amdgcn_mfma_f32_16x16x32_bf16(Ah2[i], Bh[j], acc[i][j], 0, 0, 0);
                        acc[i][j] = __builtin_amdgcn_mfma_f32_16x16x32_bf16(Ah2[i], Bl[j], acc[i][j], 0, 0, 0);
                        acc[i][j] = __builtin_amdgcn_mfma_f32_16x16x32_bf16(Al2[i], Bh[j], acc[i][j], 0, 0, 0);
                    }
                __builtin_amdgcn_s_setprio(0);
            }
            if (tap < 8) {
                int nb = (tap + 1) & 1;
                *(uint4*)&smem[AH[nb] + la] = nh;
                *(uint4*)&smem[AL[nb] + la] = nl;
            }
        }
    }

    const int h = h0 + wx;
    #pragma unroll
    for (int i = 0; i < 2; ++i)
        #pragma unroll
        for (int j = 0; j < 2; ++j)
            #pragma unroll
            for (int r = 0; r < 4; ++r) {
                int o = o0 + wy * 32 + i * 16 + quad * 4 + r;
                int w = j * 16 + ln;
                out[(size_t)(b * CO_ + o) * N_ + h * 32 + w] = acc[i][j][r];
            }
}

// ---------------------------------------------------------------------------
extern "C" void kernel_launch(void* const* d_in, const int* in_sizes, int n_in,
                              void* d_out, int out_size, void* d_ws, size_t ws_size,
                              hipStream_t stream) {
    const float* x   = (const float*)d_in[0];
    const float* Wq  = (const float*)d_in[1];
    const float* Wk  = (const float*)d_in[2];
    const float* Wv  = (const float*)d_in[3];
    const float* w1d = (const float*)d_in[4];
    const float* Wc  = (const float*)d_in[5];

    float* out  = (float*)d_out;
    float* gate = out + 2097152;
    float* ca   = gate + 8388608;

    float*    gv      = (float*)d_ws;            // 1048576 f  [b][n][c] layout
    float*    meanb   = gv + 1048576;            // 1024 f (sum over n)
    ushort_t* Whi     = (ushort_t*)(meanb + 1024);   // 294912
    ushort_t* Wlo     = Whi + 294912;
    ushort_t* Wp_hi   = Wlo + 294912;            // 98304
    ushort_t* Wp_lo   = Wp_hi + 98304;
    ushort_t* xs_hi   = Wp_lo + 98304;           // 2097152
    ushort_t* xs_lo   = xs_hi + 2097152;
    ushort_t* qt_hi   = xs_lo + 2097152;         // 1048576
    ushort_t* qt_lo   = qt_hi + 1048576;
    ushort_t* kt_hi   = qt_lo + 1048576;
    ushort_t* kt_lo   = kt_hi + 1048576;
    ushort_t* vB_hi   = kt_lo + 1048576;         // 1048576 (packed [b][m>>5][c][m&31])
    ushort_t* vB_lo   = vB_hi + 1048576;
    ushort_t* gvh     = vB_lo + 1048576;         // 1048576 ([b][n][c], gv*ca hi)
    ushort_t* gvl     = gvh + 1048576;

    static bool s_attr_done = false;
    if (!s_attr_done) {
        hipFuncSetAttribute((const void*)conv_mfma_kernel,
                            hipFuncAttributeMaxDynamicSharedMemorySize, 84992);
        s_attr_done = true;
    }

    prep_all_kernel<<<dim3(2560), 256, 0, stream>>>(
        x, Wc, Wq, Wk, Wv, Whi, Wlo, Wp_hi, Wp_lo, xs_hi, xs_lo, meanb);
    proj_mfma_kernel<<<dim3(16, 6, 8), 256, 0, stream>>>(
        Wp_hi, Wp_lo, xs_hi, xs_lo, qt_hi, qt_lo, kt_hi, kt_lo, vB_hi, vB_lo);
    attn_fused_kernel<<<dim3(32, 8), 512, 0, stream>>>(
        qt_hi, qt_lo, kt_hi, kt_lo, vB_hi, vB_lo, gate, gv, meanb);
    gvca_prep_kernel<<<dim3(256), 256, 0, stream>>>(
        gv, meanb, w1d, gvh, gvl, ca);
    conv_mfma_kernel<<<dim3(256), 512, 84992, stream>>>(
        gvh, gvl, Whi, Wlo, out);
}

// Round 8
// 265.060 us; speedup vs baseline: 1.0477x; 1.0386x over previous
//
#include <hip/hip_runtime.h>
#include <math.h>

#define B_   8
#define C_   256
#define CI_  128
#define N_   1024
#define HW_  32
#define CO_  256

typedef __bf16 v8bf __attribute__((ext_vector_type(8)));
typedef float  f32x4 __attribute__((ext_vector_type(4)));
typedef unsigned short ushort_t;

__device__ __forceinline__ unsigned short f2bf_rne(float f) {
    unsigned int u = __float_as_uint(f);
    unsigned int r = u + 0x7FFF + ((u >> 16) & 1);
    return (unsigned short)(r >> 16);
}
__device__ __forceinline__ float bf2f(unsigned short h) {
    return __uint_as_float(((unsigned int)h) << 16);
}
__device__ __forceinline__ v8bf ld8(const ushort_t* p) {
    return *(const v8bf*)p;
}

// ---------------------------------------------------------------------------
// P1: W splits only (x-gather lives in proj_fused).
// blocks [0,1152): Wc -> Whi/Wlo [o][tap][ci]; block 0 zeroes meanb.
// blocks [1152,1536): Wq/Wk/Wv -> Wp hi/lo [384][256].
__global__ __launch_bounds__(256) void prep_all_kernel(
    const float* __restrict__ Wc,
    const float* __restrict__ Wq, const float* __restrict__ Wk,
    const float* __restrict__ Wv,
    ushort_t* __restrict__ Whi, ushort_t* __restrict__ Wlo,
    ushort_t* __restrict__ Wp_hi, ushort_t* __restrict__ Wp_lo,
    float* __restrict__ meanb)
{
    const int bx = blockIdx.x;
    const int tid = threadIdx.x;

    if (bx < 1152) {
        if (bx == 0) {   // zero the mean accumulator (1024 floats)
            *(float4*)&meanb[tid * 4] = make_float4(0.f, 0.f, 0.f, 0.f);
        }
        int idx = bx * 256 + tid;                 // 294912
        int o = idx / 1152;
        int r = idx - o * 1152;
        int ci = r / 9;
        int tap = r - ci * 9;
        float v = Wc[idx];
        unsigned short h = f2bf_rne(v);
        unsigned short l = f2bf_rne(v - bf2f(h));
        int didx = o * 1152 + tap * 128 + ci;
        Whi[didx] = h; Wlo[didx] = l;
    } else {
        int j = (bx - 1152) * 256 + tid;          // 98304
        int o = j >> 8, c = j & 255;
        float v = (o < 128) ? Wq[o * 256 + c]
                : (o < 256) ? Wk[(o - 128) * 256 + c]
                            : Wv[(o - 256) * 256 + c];
        unsigned short h = f2bf_rne(v);
        unsigned short l = f2bf_rne(v - bf2f(h));
        Wp_hi[j] = h; Wp_lo[j] = l;
    }
}

// ---------------------------------------------------------------------------
// K1 (fused): per block = one (batch, 32-row n-tile). Gathers its own strided
// x panel straight into swizzled LDS (hi/lo bf16), then computes ALL 384
// projection rows with the 3-term MFMA. Subtile assignment is WAVE-INTERLEAVED
// stride-4: st = wv + 4*t, so roles are COMPILE-TIME for every wave:
//   t in {0,1} -> q (st 0..7), t in {2,3} -> k (st 8..15), t in {4,5} -> v.
// No runtime branch in the K-loop (the construct suspected in the R5 failure).
// v-subtiles use operand-swapped MFMA (same product set) -> reg dim = m.
__global__ __launch_bounds__(256) void proj_fused_kernel(
    const float* __restrict__ x,
    const ushort_t* __restrict__ Wp_hi, const ushort_t* __restrict__ Wp_lo,
    ushort_t* __restrict__ qt_hi, ushort_t* __restrict__ qt_lo,
    ushort_t* __restrict__ kt_hi, ushort_t* __restrict__ kt_lo,
    ushort_t* __restrict__ vB_hi, ushort_t* __restrict__ vB_lo)
{
    __shared__ __align__(16) char xsm[32768];   // xh[32][512B] + xl[32][512B], swizzled
    const int lin = blockIdx.x;
    const int b  = lin & 7;            // XCD pin
    const int n5 = lin >> 3;           // 0..31 (n-tile AND spatial h index)
    const int n0 = n5 * 32;
    const int tid = threadIdx.x;

    // ---- gather: row w of tile = spatial (h=n5, w) -> channels c
    {
        const int w = tid & 31, cg = tid >> 5;   // cg in [0,8)
        #pragma unroll
        for (int j = 0; j < 4; ++j) {
            const int cbase = j * 64 + cg * 8;
            float v[8];
            #pragma unroll
            for (int i = 0; i < 8; ++i)
                v[i] = x[((size_t)(b * C_ + cbase + i) * 128 + n5 * 4) * 128 + w * 4];
            unsigned int hw[4], lw[4];
            #pragma unroll
            for (int p = 0; p < 4; ++p) {
                unsigned short h0 = f2bf_rne(v[2 * p]);
                unsigned short l0 = f2bf_rne(v[2 * p] - bf2f(h0));
                unsigned short h1 = f2bf_rne(v[2 * p + 1]);
                unsigned short l1 = f2bf_rne(v[2 * p + 1] - bf2f(h1));
                hw[p] = (unsigned)h0 | ((unsigned)h1 << 16);
                lw[p] = (unsigned)l0 | ((unsigned)l1 << 16);
            }
            const int chunk = j * 8 + cg;        // 16B chunk index (c/8)
            const int addr = w * 512 + ((chunk ^ (w & 7)) << 4);
            *(uint4*)&xsm[addr]         = make_uint4(hw[0], hw[1], hw[2], hw[3]);
            *(uint4*)&xsm[16384 + addr] = make_uint4(lw[0], lw[1], lw[2], lw[3]);
        }
    }
    __syncthreads();

    const int l = tid & 63, wv = tid >> 6;       // wv in [0,4)
    const int ln = l & 15, quad = l >> 4;

    f32x4 acc[6][2];
    #pragma unroll
    for (int t = 0; t < 6; ++t)
        #pragma unroll
        for (int j = 0; j < 2; ++j) acc[t][j] = (f32x4){0.f,0.f,0.f,0.f};

    // ---- K loop: A from global Wp (L2-hot), B from LDS tile
    #pragma unroll 2
    for (int k0 = 0; k0 < 256; k0 += 32) {
        v8bf Bh[2], Bl[2];
        #pragma unroll
        for (int j = 0; j < 2; ++j) {
            int row = j * 16 + ln;
            int chunk = (k0 >> 3) + quad;
            int addr = row * 512 + ((chunk ^ (row & 7)) << 4);
            Bh[j] = *(const v8bf*)&xsm[addr];
            Bl[j] = *(const v8bf*)&xsm[16384 + addr];
        }
        v8bf Ah[6], Al[6];
        #pragma unroll
        for (int t = 0; t < 6; ++t) {
            int st = wv + 4 * t;                 // subtile row-block
            size_t off = (size_t)(st * 16 + ln) * 256 + k0 + quad * 8;
            Ah[t] = ld8(Wp_hi + off); Al[t] = ld8(Wp_lo + off);
        }
        __builtin_amdgcn_s_setprio(1);
        // q/k subtiles (t=0..3): rows = o (reg), cols = n (lane)
        #pragma unroll
        for (int t = 0; t < 4; ++t)
            #pragma unroll
            for (int j = 0; j < 2; ++j) {
                acc[t][j] = __builtin_amdgcn_mfma_f32_16x16x32_bf16(Ah[t], Bh[j], acc[t][j], 0, 0, 0);
                acc[t][j] = __builtin_amdgcn_mfma_f32_16x16x32_bf16(Ah[t], Bl[j], acc[t][j], 0, 0, 0);
                acc[t][j] = __builtin_amdgcn_mfma_f32_16x16x32_bf16(Al[t], Bh[j], acc[t][j], 0, 0, 0);
            }
        // v subtiles (t=4,5): operand-swapped -> rows = m (reg), cols = c (lane)
        #pragma unroll
        for (int t = 4; t < 6; ++t)
            #pragma unroll
            for (int j = 0; j < 2; ++j) {
                acc[t][j] = __builtin_amdgcn_mfma_f32_16x16x32_bf16(Bh[j], Ah[t], acc[t][j], 0, 0, 0);
                acc[t][j] = __builtin_amdgcn_mfma_f32_16x16x32_bf16(Bh[j], Al[t], acc[t][j], 0, 0, 0);
                acc[t][j] = __builtin_amdgcn_mfma_f32_16x16x32_bf16(Bl[j], Ah[t], acc[t][j], 0, 0, 0);
            }
        __builtin_amdgcn_s_setprio(0);
    }

    // ---- epilogue: t=0,1 -> q (st = wv, wv+4); t=2,3 -> k (st-8); t=4,5 -> v
    #pragma unroll
    for (int t = 0; t < 4; ++t) {
        const int st = wv + 4 * t;
        ushort_t* th = (t < 2) ? qt_hi : kt_hi;
        ushort_t* tl = (t < 2) ? qt_lo : kt_lo;
        const int oo = (st & 7) * 16 + quad * 4;
        #pragma unroll
        for (int j = 0; j < 2; ++j) {
            int n = n0 + j * 16 + ln;
            unsigned int h01 = 0, h23 = 0, l01 = 0, l23 = 0;
            #pragma unroll
            for (int r = 0; r < 4; ++r) {
                float f = acc[t][j][r];
                unsigned short hh = f2bf_rne(f);
                unsigned short lo = f2bf_rne(f - bf2f(hh));
                if (r < 2) { h01 |= ((unsigned)hh) << (16 * r); l01 |= ((unsigned)lo) << (16 * r); }
                else       { h23 |= ((unsigned)hh) << (16 * (r - 2)); l23 |= ((unsigned)lo) << (16 * (r - 2)); }
            }
            size_t off = ((size_t)(b * N_) + n) * 128 + oo;
            *(uint2*)&th[off] = make_uint2(h01, h23);
            *(uint2*)&tl[off] = make_uint2(l01, l23);
        }
    }
    #pragma unroll
    for (int t = 4; t < 6; ++t) {
        const int st = wv + 4 * t;               // 16..23
        const int c = (st - 16) * 16 + ln;
        #pragma unroll
        for (int j = 0; j < 2; ++j) {
            int mlo = j * 16 + quad * 4;
            unsigned int h01 = 0, h23 = 0, l01 = 0, l23 = 0;
            #pragma unroll
            for (int r = 0; r < 4; ++r) {
                float f = acc[t][j][r];
                unsigned short hh = f2bf_rne(f);
                unsigned short lo = f2bf_rne(f - bf2f(hh));
                if (r < 2) { h01 |= ((unsigned)hh) << (16 * r); l01 |= ((unsigned)lo) << (16 * r); }
                else       { h23 |= ((unsigned)hh) << (16 * (r - 2)); l23 |= ((unsigned)lo) << (16 * (r - 2)); }
            }
            size_t off = (((size_t)b * 32 + n5) * 128 + c) * 32 + mlo;
            *(uint2*)&vB_hi[off] = make_uint2(h01, h23);
            *(uint2*)&vB_lo[off] = make_uint2(l01, l23);
        }
    }
}

// ---------------------------------------------------------------------------
// K2: fused attention, 512 threads / 8 waves, XCD-pinned. Gate fp32 store
// deferred past phase 2. Accumulates mean partials (atomicAdd).
__global__ __launch_bounds__(512, 2) void attn_fused_kernel(
    const ushort_t* __restrict__ qt_hi, const ushort_t* __restrict__ qt_lo,
    const ushort_t* __restrict__ kt_hi, const ushort_t* __restrict__ kt_lo,
    const ushort_t* __restrict__ vB_hi, const ushort_t* __restrict__ vB_lo,
    float* __restrict__ gate, float* __restrict__ gv, float* __restrict__ meanb)
{
    __shared__ __align__(16) char gsm[65536];     // Gbf[32][1024] bf16, swizzled
    __shared__ float redA[8][32];
    __shared__ float redB[8][32];

    const int lin = blockIdx.x + 32 * blockIdx.y;
    const int b  = lin & 7;            // XCD pin
    const int n0 = (lin >> 3) * 32;
    const int tid = threadIdx.x;
    const int l = tid & 63, w = tid >> 6;         // w in [0,8)
    const int ln = l & 15, quad = l >> 4;
    const int Mw = w * 128;

    const ushort_t* qb_h = qt_hi + ((size_t)(b * N_) + n0) * 128;
    const ushort_t* qb_l = qt_lo + ((size_t)(b * N_) + n0) * 128;
    const ushort_t* kb_h = kt_hi + (size_t)(b * N_) * 128;
    const ushort_t* kb_l = kt_lo + (size_t)(b * N_) * 128;

    f32x4 acc[2][8];
    #pragma unroll
    for (int nt = 0; nt < 2; ++nt)
        #pragma unroll
        for (int mt = 0; mt < 8; ++mt) acc[nt][mt] = (f32x4){0.f,0.f,0.f,0.f};

    // ---- phase 1: scores (3-term bf16 split)
    #pragma unroll
    for (int c0 = 0; c0 < 128; c0 += 32) {
        v8bf Ah[2], Al[2];
        #pragma unroll
        for (int nt = 0; nt < 2; ++nt) {
            size_t aoff = (size_t)(nt * 16 + ln) * 128 + c0 + quad * 8;
            Ah[nt] = ld8(qb_h + aoff); Al[nt] = ld8(qb_l + aoff);
        }
        #pragma unroll
        for (int mt = 0; mt < 8; ++mt) {
            size_t boff = (size_t)(Mw + mt * 16 + ln) * 128 + c0 + quad * 8;
            v8bf Bh = ld8(kb_h + boff);
            v8bf Bl = ld8(kb_l + boff);
            __builtin_amdgcn_s_setprio(1);
            #pragma unroll
            for (int nt = 0; nt < 2; ++nt) {
                acc[nt][mt] = __builtin_amdgcn_mfma_f32_16x16x32_bf16(Ah[nt], Bh, acc[nt][mt], 0, 0, 0);
                acc[nt][mt] = __builtin_amdgcn_mfma_f32_16x16x32_bf16(Ah[nt], Bl, acc[nt][mt], 0, 0, 0);
                acc[nt][mt] = __builtin_amdgcn_mfma_f32_16x16x32_bf16(Al[nt], Bh, acc[nt][mt], 0, 0, 0);
            }
            __builtin_amdgcn_s_setprio(0);
        }
    }

    // ---- softmax
    float rmax[2][4];
    #pragma unroll
    for (int nt = 0; nt < 2; ++nt)
        #pragma unroll
        for (int r = 0; r < 4; ++r) {
            float m = acc[nt][0][r];
            #pragma unroll
            for (int mt = 1; mt < 8; ++mt) m = fmaxf(m, acc[nt][mt][r]);
            rmax[nt][r] = m;
        }
    #pragma unroll
    for (int nt = 0; nt < 2; ++nt)
        #pragma unroll
        for (int r = 0; r < 4; ++r) {
            float m = rmax[nt][r];
            #pragma unroll
            for (int xm = 1; xm <= 8; xm <<= 1) m = fmaxf(m, __shfl_xor(m, xm, 64));
            rmax[nt][r] = m;
        }
    if (ln == 0) {
        #pragma unroll
        for (int nt = 0; nt < 2; ++nt)
            #pragma unroll
            for (int r = 0; r < 4; ++r)
                redA[w][nt * 16 + quad * 4 + r] = rmax[nt][r];
    }
    __syncthreads();
    #pragma unroll
    for (int nt = 0; nt < 2; ++nt)
        #pragma unroll
        for (int r = 0; r < 4; ++r) {
            int row = nt * 16 + quad * 4 + r;
            float m0 = fmaxf(fmaxf(redA[0][row], redA[1][row]),
                             fmaxf(redA[2][row], redA[3][row]));
            float m1 = fmaxf(fmaxf(redA[4][row], redA[5][row]),
                             fmaxf(redA[6][row], redA[7][row]));
            rmax[nt][r] = fmaxf(m0, m1);
        }

    float rsum[2][4];
    #pragma unroll
    for (int nt = 0; nt < 2; ++nt)
        #pragma unroll
        for (int r = 0; r < 4; ++r) {
            float s = 0.f;
            #pragma unroll
            for (int mt = 0; mt < 8; ++mt) {
                float e = __expf(acc[nt][mt][r] - rmax[nt][r]);
                acc[nt][mt][r] = e;
                s += e;
            }
            rsum[nt][r] = s;
        }
    #pragma unroll
    for (int nt = 0; nt < 2; ++nt)
        #pragma unroll
        for (int r = 0; r < 4; ++r) {
            float s = rsum[nt][r];
            #pragma unroll
            for (int xm = 1; xm <= 8; xm <<= 1) s += __shfl_xor(s, xm, 64);
            rsum[nt][r] = s;
        }
    if (ln == 0) {
        #pragma unroll
        for (int nt = 0; nt < 2; ++nt)
            #pragma unroll
            for (int r = 0; r < 4; ++r)
                redB[w][nt * 16 + quad * 4 + r] = rsum[nt][r];
    }
    __syncthreads();
    #pragma unroll
    for (int nt = 0; nt < 2; ++nt)
        #pragma unroll
        for (int r = 0; r < 4; ++r) {
            int row = nt * 16 + quad * 4 + r;
            float inv = 1.0f / ((redB[0][row] + redB[1][row] + redB[2][row] + redB[3][row]) +
                                (redB[4][row] + redB[5][row] + redB[6][row] + redB[7][row]));
            #pragma unroll
            for (int mt = 0; mt < 8; ++mt) acc[nt][mt][r] *= inv;
        }

    // ---- write gate bf16 -> swizzled LDS only (fp32 global store deferred)
    #pragma unroll
    for (int nt = 0; nt < 2; ++nt)
        #pragma unroll
        for (int r = 0; r < 4; ++r) {
            int nl = nt * 16 + quad * 4 + r;
            #pragma unroll
            for (int mt = 0; mt < 8; ++mt) {
                int m = Mw + mt * 16 + ln;
                int chunk = m >> 3;
                int addr = nl * 2048 + (((chunk ^ (nl & 7))) << 4) + ((m & 7) << 1);
                *(ushort_t*)&gsm[addr] = f2bf_rne(acc[nt][mt][r]);
            }
        }
    __syncthreads();

    // ---- phase 2: gv[n][c] = sum_m gate[n][m]*v[c][m]; wave owns c-slice w*16
    const ushort_t* vb_h = vB_hi + (size_t)b * CI_ * N_;
    const ushort_t* vb_l = vB_lo + (size_t)b * CI_ * N_;

    f32x4 acc2[2];
    acc2[0] = (f32x4){0.f,0.f,0.f,0.f};
    acc2[1] = (f32x4){0.f,0.f,0.f,0.f};

    #pragma unroll 4
    for (int m0 = 0; m0 < 1024; m0 += 32) {
        v8bf Bg[2];
        #pragma unroll
        for (int nt = 0; nt < 2; ++nt) {
            int nl = nt * 16 + ln;
            int chunk = (m0 >> 3) + quad;
            Bg[nt] = *(const v8bf*)&gsm[nl * 2048 + (((chunk ^ (nl & 7))) << 4)];
        }
        int c = w * 16 + ln;
        size_t aoff = (((size_t)(m0 >> 5)) * 128 + c) * 32 + quad * 8;
        v8bf Avh = ld8(vb_h + aoff);
        v8bf Avl = ld8(vb_l + aoff);
        __builtin_amdgcn_s_setprio(1);
        #pragma unroll
        for (int nt = 0; nt < 2; ++nt) {
            acc2[nt] = __builtin_amdgcn_mfma_f32_16x16x32_bf16(Avh, Bg[nt], acc2[nt], 0, 0, 0);
            acc2[nt] = __builtin_amdgcn_mfma_f32_16x16x32_bf16(Avl, Bg[nt], acc2[nt], 0, 0, 0);
        }
        __builtin_amdgcn_s_setprio(0);
    }

    // gv in [b][n][c] layout, float4 (4 consecutive c per lane)
    #pragma unroll
    for (int nt = 0; nt < 2; ++nt) {
        int n = n0 + nt * 16 + ln;
        float4 o4 = make_float4(acc2[nt][0], acc2[nt][1], acc2[nt][2], acc2[nt][3]);
        *(float4*)&gv[((size_t)(b * N_) + n) * CI_ + w * 16 + quad * 4] = o4;
    }

    // ---- deferred gate fp32 global store
    float* grow = gate + (size_t)b * N_ * N_;
    #pragma unroll
    for (int nt = 0; nt < 2; ++nt)
        #pragma unroll
        for (int r = 0; r < 4; ++r) {
            int n = n0 + nt * 16 + quad * 4 + r;
            #pragma unroll
            for (int mt = 0; mt < 8; ++mt) {
                int m = Mw + mt * 16 + ln;
                grow[(size_t)n * N_ + m] = acc[nt][mt][r];
            }
        }

    // mean partials
    float s0 = acc2[0][0] + acc2[1][0];
    float s1 = acc2[0][1] + acc2[1][1];
    float s2 = acc2[0][2] + acc2[1][2];
    float s3 = acc2[0][3] + acc2[1][3];
    #pragma unroll
    for (int xm = 1; xm <= 8; xm <<= 1) {
        s0 += __shfl_xor(s0, xm, 64);
        s1 += __shfl_xor(s1, xm, 64);
        s2 += __shfl_xor(s2, xm, 64);
        s3 += __shfl_xor(s3, xm, 64);
    }
    if (ln == 0) {
        int cb = b * CI_ + w * 16 + quad * 4;
        atomicAdd(&meanb[cb + 0], s0);
        atomicAdd(&meanb[cb + 1], s1);
        atomicAdd(&meanb[cb + 2], s2);
        atomicAdd(&meanb[cb + 3], s3);
    }
}

// ---------------------------------------------------------------------------
// K3: gv*ca -> bf16 hi/lo split, ONCE. Also computes+writes ca.
__global__ __launch_bounds__(256) void gvca_prep_kernel(
    const float* __restrict__ gv, const float* __restrict__ meanb,
    const float* __restrict__ w1d,
    ushort_t* __restrict__ gvh, ushort_t* __restrict__ gvl,
    float* __restrict__ ca_out)
{
    __shared__ float ca_s[128];
    const int lin = blockIdx.x;
    const int b  = lin & 7;            // XCD pin
    const int ns = lin >> 3;           // 0..31
    const int tid = threadIdx.x;

    if (tid < 128) {
        const float sc = 1.0f / 1024.0f;
        int t = b * 128 + tid;
        float left  = (tid > 0)   ? meanb[t - 1] * sc : 0.0f;
        float mid   = meanb[t] * sc;
        float right = (tid < 127) ? meanb[t + 1] * sc : 0.0f;
        float val = w1d[0] * left + w1d[1] * mid + w1d[2] * right;
        float s = 1.0f / (1.0f + __expf(-val));
        ca_s[tid] = s;
        if (ns == 0) ca_out[t] = s;
    }
    __syncthreads();

    const int cl = (tid & 31) * 4;
    const int nr = tid >> 5;           // 0..7
    #pragma unroll
    for (int i = 0; i < 4; ++i) {
        int n = ns * 32 + nr + i * 8;
        size_t off = ((size_t)(b * N_) + n) * 128 + cl;
        float4 v4 = *(const float4*)&gv[off];
        float vv[4] = { v4.x * ca_s[cl], v4.y * ca_s[cl + 1],
                        v4.z * ca_s[cl + 2], v4.w * ca_s[cl + 3] };
        unsigned int h01 = 0, h23 = 0, l01 = 0, l23 = 0;
        #pragma unroll
        for (int t = 0; t < 4; ++t) {
            unsigned short h = f2bf_rne(vv[t]);
            unsigned short lo = f2bf_rne(vv[t] - bf2f(h));
            if (t < 2) { h01 |= ((unsigned)h) << (16 * t); l01 |= ((unsigned)lo) << (16 * t); }
            else       { h23 |= ((unsigned)h) << (16 * (t - 2)); l23 |= ((unsigned)lo) << (16 * (t - 2)); }
        }
        *(uint2*)&gvh[off] = make_uint2(h01, h23);
        *(uint2*)&gvl[off] = make_uint2(l01, l23);
    }
}

// ---------------------------------------------------------------------------
// K7: MFMA conv: 512 threads, 4 h-rows per block, 64 o-rows. 256 blocks,
// 85 KB dynamic LDS, B-stage pure uint4 copies of pre-split gv*ca.
#define CV_BHI  0
#define CV_BLO  26112
__global__ __launch_bounds__(512, 1) void conv_mfma_kernel(
    const ushort_t* __restrict__ gvh, const ushort_t* __restrict__ gvl,
    const ushort_t* __restrict__ Whi, const ushort_t* __restrict__ Wlo,
    float* __restrict__ out)
{
    extern __shared__ __align__(16) char smem[];
    const int AH[2] = {52224, 68608};
    const int AL[2] = {60416, 76800};

    const int lin = blockIdx.x;
    const int b    = lin & 7;          // XCD pin
    const int rest = lin >> 3;         // 0..31
    const int o0 = (rest & 3) * 64;
    const int h0 = (rest >> 2) * 4;
    const int tid = threadIdx.x;
    const int l   = tid & 63;
    const int wv  = tid >> 6;          // 0..7
    const int wy  = wv >> 2;           // 0..1 : o-subrange
    const int wx  = wv & 3;            // 0..3 : h-row
    const int ln  = l & 15;
    const int quad = l >> 4;

    f32x4 acc[2][2];
    #pragma unroll
    for (int i = 0; i < 2; ++i)
        #pragma unroll
        for (int j = 0; j < 2; ++j)
            acc[i][j] = (f32x4){0.f, 0.f, 0.f, 0.f};

    const int srow = tid >> 3, scol = tid & 7;   // A-stage: 64 rows x 8 slots
    const int la   = srow * 128 + scol * 16;
    const int csrc = scol ^ (srow & 7);

    for (int half = 0; half < 2; ++half) {
        __syncthreads();   // previous half fully consumed
        // ---- stage B: 6 h-rows x 34 cols halo tile of pre-split gv*ca
        for (int u = tid; u < 204 * 8; u += 512) {
            int p  = u >> 3;
            int cs = u & 7;
            int hrel = p / 34;
            int c    = p - hrel * 34;
            int gr = h0 + hrel - 1;
            int gc = c - 1;
            bool ok = ((unsigned)gr < 32u) && ((unsigned)gc < 32u);
            uint4 h4 = make_uint4(0, 0, 0, 0), l4 = make_uint4(0, 0, 0, 0);
            if (ok) {
                size_t src = ((size_t)(b * N_) + gr * 32 + gc) * 128 + half * 64 + cs * 8;
                h4 = *(const uint4*)&gvh[src];
                l4 = *(const uint4*)&gvl[src];
            }
            int addr = p * 128 + ((cs ^ (p & 7)) << 4);
            *(uint4*)&smem[CV_BHI + addr] = h4;
            *(uint4*)&smem[CV_BLO + addr] = l4;
        }
        // ---- preload A(tap=0) into buffer 0 (1 slot per thread)
        {
            size_t g = (size_t)(o0 + srow) * 1152 + half * 64 + csrc * 8;
            *(uint4*)&smem[AH[0] + la] = *(const uint4*)&Whi[g];
            *(uint4*)&smem[AL[0] + la] = *(const uint4*)&Wlo[g];
        }

        for (int tap = 0; tap < 9; ++tap) {
            __syncthreads();   // buf[tap&1] + B ready; buf[(tap+1)&1] free
            uint4 nh, nl;
            if (tap < 8) {
                size_t g = (size_t)(o0 + srow) * 1152 + (tap + 1) * 128 + half * 64 + csrc * 8;
                nh = *(const uint4*)&Whi[g];
                nl = *(const uint4*)&Wlo[g];
            }
            const int ah = AH[tap & 1], al = AL[tap & 1];
            const int dy = tap / 3, dx = tap - dy * 3;
            const int pbase = (wx + dy) * 34 + dx;
            #pragma unroll
            for (int cc = 0; cc < 2; ++cc) {
                v8bf Bh[2], Bl[2], Ah2[2], Al2[2];
                #pragma unroll
                for (int j = 0; j < 2; ++j) {
                    int p = pbase + j * 16 + ln;
                    int ch = cc * 4 + quad;
                    int addr = p * 128 + ((ch ^ (p & 7)) << 4);
                    Bh[j] = *(const v8bf*)&smem[CV_BHI + addr];
                    Bl[j] = *(const v8bf*)&smem[CV_BLO + addr];
                }
                #pragma unroll
                for (int i = 0; i < 2; ++i) {
                    int o = wy * 32 + i * 16 + ln;
                    int ch = cc * 4 + quad;
                    int addr = o * 128 + ((ch ^ (o & 7)) << 4);
                    Ah2[i] = *(const v8bf*)&smem[ah + addr];
                    Al2[i] = *(const v8bf*)&smem[al + addr];
                }
                __builtin_amdgcn_s_setprio(1);
                #pragma unroll
                for (int i = 0; i < 2; ++i)
                    #pragma unroll
                    for (int j = 0; j < 2; ++j) {
                        acc[i][j] = __builtin_amdgcn_mfma_f32_16x16x32_bf16(Ah2[i], Bh[j], acc[i][j], 0, 0, 0);
                        acc[i][j] = __builtin_amdgcn_mfma_f32_16x16x32_bf16(Ah2[i], Bl[j], acc[i][j], 0, 0, 0);
                        acc[i][j] = __builtin_amdgcn_mfma_f32_16x16x32_bf16(Al2[i], Bh[j], acc[i][j], 0, 0, 0);
                    }
                __builtin_amdgcn_s_setprio(0);
            }
            if (tap < 8) {
                int nb = (tap + 1) & 1;
                *(uint4*)&smem[AH[nb] + la] = nh;
                *(uint4*)&smem[AL[nb] + la] = nl;
            }
        }
    }

    const int h = h0 + wx;
    #pragma unroll
    for (int i = 0; i < 2; ++i)
        #pragma unroll
        for (int j = 0; j < 2; ++j)
            #pragma unroll
            for (int r = 0; r < 4; ++r) {
                int o = o0 + wy * 32 + i * 16 + quad * 4 + r;
                int w = j * 16 + ln;
                out[(size_t)(b * CO_ + o) * N_ + h * 32 + w] = acc[i][j][r];
            }
}

// ---------------------------------------------------------------------------
extern "C" void kernel_launch(void* const* d_in, const int* in_sizes, int n_in,
                              void* d_out, int out_size, void* d_ws, size_t ws_size,
                              hipStream_t stream) {
    const float* x   = (const float*)d_in[0];
    const float* Wq  = (const float*)d_in[1];
    const float* Wk  = (const float*)d_in[2];
    const float* Wv  = (const float*)d_in[3];
    const float* w1d = (const float*)d_in[4];
    const float* Wc  = (const float*)d_in[5];

    float* out  = (float*)d_out;
    float* gate = out + 2097152;
    float* ca   = gate + 8388608;

    float*    gv      = (float*)d_ws;            // 1048576 f  [b][n][c] layout
    float*    meanb   = gv + 1048576;            // 1024 f (sum over n)
    ushort_t* Whi     = (ushort_t*)(meanb + 1024);   // 294912
    ushort_t* Wlo     = Whi + 294912;
    ushort_t* Wp_hi   = Wlo + 294912;            // 98304
    ushort_t* Wp_lo   = Wp_hi + 98304;
    ushort_t* qt_hi   = Wp_lo + 98304;           // 1048576
    ushort_t* qt_lo   = qt_hi + 1048576;
    ushort_t* kt_hi   = qt_lo + 1048576;
    ushort_t* kt_lo   = kt_hi + 1048576;
    ushort_t* vB_hi   = kt_lo + 1048576;         // 1048576 (packed [b][m>>5][c][m&31])
    ushort_t* vB_lo   = vB_hi + 1048576;
    ushort_t* gvh     = vB_lo + 1048576;         // 1048576 ([b][n][c], gv*ca hi)
    ushort_t* gvl     = gvh + 1048576;

    static bool s_attr_done = false;
    if (!s_attr_done) {
        hipFuncSetAttribute((const void*)conv_mfma_kernel,
                            hipFuncAttributeMaxDynamicSharedMemorySize, 84992);
        s_attr_done = true;
    }

    prep_all_kernel<<<dim3(1536), 256, 0, stream>>>(
        Wc, Wq, Wk, Wv, Whi, Wlo, Wp_hi, Wp_lo, meanb);
    proj_fused_kernel<<<dim3(256), 256, 0, stream>>>(
        x, Wp_hi, Wp_lo, qt_hi, qt_lo, kt_hi, kt_lo, vB_hi, vB_lo);
    attn_fused_kernel<<<dim3(32, 8), 512, 0, stream>>>(
        qt_hi, qt_lo, kt_hi, kt_lo, vB_hi, vB_lo, gate, gv, meanb);
    gvca_prep_kernel<<<dim3(256), 256, 0, stream>>>(
        gv, meanb, w1d, gvh, gvl, ca);
    conv_mfma_kernel<<<dim3(256), 512, 84992, stream>>>(
        gvh, gvl, Whi, Wlo, out);
}